// Round 19
// baseline (98.451 us; speedup 1.0000x reference)
//
#include <hip/hip_runtime.h>

// B=4, H=W=64, N=4096, C=512, HEAD=8, dh=64, SR=4, Nk=256
// Full bf16 pipeline (validated: absmax 3.66e-4 vs 1.26e-3 threshold):
//   all GEMMs pure bf16 (K=512, 8 K-steps), fp32 MFMA accumulate;
//   attn QK 1-term, PV 1-term; Q/K/V/attno hi-only; conv partials bf16.
// r19: critical-chain reorder — q-proj joins conv (both depend only on prep);
//   kvproj is its own short launch after ln.

typedef __bf16 bf16x8 __attribute__((ext_vector_type(8)));
typedef float f32x4 __attribute__((ext_vector_type(4)));

__device__ __forceinline__ ushort f2bf(float v) {
  uint u = __float_as_uint(v);
  return (ushort)((u + 0x7FFFu + ((u >> 16) & 1u)) >> 16);
}
__device__ __forceinline__ float bf2f(ushort h) {
  return __uint_as_float((uint)h << 16);
}
__device__ __forceinline__ void gload16(const void* g, void* l) {
  __builtin_amdgcn_global_load_lds(
      (const __attribute__((address_space(1))) void*)g,
      (__attribute__((address_space(3))) void*)l, 16, 0, 0);
}
// bijective XCD swizzle for nwg % 8 == 0
__device__ __forceinline__ int xcd_swz(int bid, int nwg) {
  int cpx = nwg >> 3;
  return (bid & 7) * cpx + (bid >> 3);
}

// ---------------- fused prep: everything -> hi-only bf16 ----------------
__global__ __launch_bounds__(256) void prep_kernel(
    const float* __restrict__ x, const float* __restrict__ Wq,
    const float* __restrict__ Wp, const float* __restrict__ Wk,
    const float* __restrict__ Wv, const float* __restrict__ Wsr,
    const float* __restrict__ bk, const float* __restrict__ bv,
    ushort* __restrict__ xq, ushort* __restrict__ Wq_,
    ushort* __restrict__ Wp_, ushort* __restrict__ Wkv_,
    ushort* __restrict__ Wsr_, float* __restrict__ bkv) {
  __shared__ float t[32][33];
  int bid = blockIdx.x, tid = threadIdx.x;
  if (bid < 4096 + 512) {
    const float* src;
    ushort* dst;
    int gid;
    if (bid < 4096) {
      src = x; dst = xq; gid = bid * 256 + tid;
    } else {
      int z = (bid - 4096) >> 7;
      src = (z == 0) ? Wq : (z == 1) ? Wp : (z == 2) ? Wk : Wv;
      dst = (z == 0) ? Wq_ : (z == 1) ? Wp_ : (z == 2) ? Wkv_ : (Wkv_ + 512 * 512);
      gid = ((bid - 4096) & 127) * 256 + tid;
    }
    int row = gid >> 6, c8 = (gid & 63) << 3;
    float4 a = *(const float4*)(src + (size_t)row * 512 + c8);
    float4 b = *(const float4*)(src + (size_t)row * 512 + c8 + 4);
    ushort h[8];
    float vv[8] = {a.x, a.y, a.z, a.w, b.x, b.y, b.z, b.w};
#pragma unroll
    for (int e = 0; e < 8; ++e) h[e] = f2bf(vv[e]);
    uint4 hp;
    hp.x = h[0] | ((uint)h[1] << 16); hp.y = h[2] | ((uint)h[3] << 16);
    hp.z = h[4] | ((uint)h[5] << 16); hp.w = h[6] | ((uint)h[7] << 16);
    *(uint4*)(dst + (size_t)row * 512 + c8) = hp;
  } else if (bid < 4096 + 512 + 4096) {
    int tb = bid - 4608;
    int z = tb >> 8, rem = tb & 255;
    int ci0 = (rem >> 4) << 5, co0 = (rem & 15) << 5;
    int tx = tid & 31, ty = tid >> 5;
#pragma unroll
    for (int i = 0; i < 32; i += 8)
      t[ty + i][tx] = Wsr[((size_t)z * 512 + ci0 + ty + i) * 512 + co0 + tx];
    __syncthreads();
#pragma unroll
    for (int i = 0; i < 32; i += 8) {
      float v = t[tx][ty + i];
      int co = co0 + ty + i, ci = ci0 + tx;
      Wsr_[((size_t)z * 512 + co) * 512 + ci] = f2bf(v);
    }
  } else {
    bkv[tid] = bk[tid]; bkv[tid + 256] = bk[tid + 256];
    bkv[tid + 512] = bv[tid]; bkv[tid + 768] = bv[tid + 256];
  }
}

// ---------------- MFMA GEMM body: pure bf16, 8 K-steps, dbuf 2-phase ----------------
// EPI=0: C fp32 + bias. EPI=1: Q hi-only per-head layout. EPI=2: Kq/Vt scatter.
template <int EPI>
__device__ __forceinline__ void gemm_body(
    const ushort* __restrict__ A, const ushort* __restrict__ Bw,
    const float* __restrict__ bias, float* __restrict__ C,
    ushort* __restrict__ Qs, ushort* __restrict__ Kq, ushort* __restrict__ Vt,
    int N, int bx, int by, ushort* lds) {
  int tid = threadIdx.x;
  int lane = tid & 63, w = tid >> 6;
  int wr = w >> 1, wc = w & 1;
  int l15 = lane & 15, g = lane >> 4;
  int srow = lane >> 3;
  int scol = (lane & 7) ^ srow;

  const ushort* aBase = A + (size_t)(by * 128 + w * 32 + srow) * 512 + scol * 8;
  const ushort* bBase = Bw + (size_t)(bx * 128 + w * 32 + srow) * 512 + scol * 8;

  f32x4 acc[4][4];
#pragma unroll
  for (int i = 0; i < 4; ++i)
#pragma unroll
    for (int j = 0; j < 4; ++j) acc[i][j] = (f32x4){0.f, 0.f, 0.f, 0.f};

#define STAGE_G(ks, buf)                                              \
  {                                                                   \
    int kk = (ks) * 64;                                               \
    ushort* aD = lds + (buf) * 16384 + w * 2048;                      \
    ushort* bD = lds + (buf) * 16384 + 8192 + w * 2048;               \
    _Pragma("unroll") for (int t = 0; t < 4; ++t) {                   \
      gload16(aBase + (size_t)t * 4096 + kk, aD + t * 512);           \
      gload16(bBase + (size_t)t * 4096 + kk, bD + t * 512);           \
    }                                                                 \
  }

#define COMPUTE_G(buf)                                                         \
  {                                                                            \
    const ushort* As = lds + (buf) * 16384;                                    \
    const ushort* Bs = As + 8192;                                              \
    _Pragma("unroll") for (int kk2 = 0; kk2 < 2; ++kk2) {                      \
      int rb = kk2 * 4 + g;                                                    \
      bf16x8 af[4], bg[4];                                                     \
      _Pragma("unroll") for (int i = 0; i < 4; ++i) {                          \
        int row = wr * 64 + i * 16 + l15;                                      \
        af[i] = *(const bf16x8*)&As[row * 64 + ((rb ^ (row & 7)) << 3)];       \
      }                                                                        \
      _Pragma("unroll") for (int j = 0; j < 4; ++j) {                          \
        int col = wc * 64 + j * 16 + l15;                                      \
        bg[j] = *(const bf16x8*)&Bs[col * 64 + ((rb ^ (col & 7)) << 3)];       \
      }                                                                        \
      _Pragma("unroll") for (int i = 0; i < 4; ++i)                            \
        _Pragma("unroll") for (int j = 0; j < 4; ++j)                          \
          acc[i][j] =                                                          \
              __builtin_amdgcn_mfma_f32_16x16x32_bf16(af[i], bg[j], acc[i][j], \
                                                      0, 0, 0);                \
    }                                                                          \
  }

  STAGE_G(0, 0);
  __syncthreads();
  for (int ks = 0; ks < 7; ++ks) {
    STAGE_G(ks + 1, (ks + 1) & 1);
    COMPUTE_G(ks & 1);
    __syncthreads();
  }
  COMPUTE_G(1);

#undef STAGE_G
#undef COMPUTE_G

  if (EPI == 0) {
#pragma unroll
    for (int j = 0; j < 4; ++j) {
      int col = bx * 128 + wc * 64 + j * 16 + l15;
      float bj = bias ? bias[col] : 0.f;
#pragma unroll
      for (int i = 0; i < 4; ++i) {
        int row0 = by * 128 + wr * 64 + i * 16 + g * 4;
#pragma unroll
        for (int r = 0; r < 4; ++r)
          C[(size_t)(row0 + r) * N + col] = acc[i][j][r] + bj;
      }
    }
  } else if (EPI == 1) {
    __syncthreads();
#pragma unroll
    for (int j = 0; j < 4; ++j) {
      int cl = wc * 64 + j * 16 + l15;
      float bj = bias[bx * 128 + cl];
#pragma unroll
      for (int i = 0; i < 4; ++i) {
        int rl0 = wr * 64 + i * 16 + g * 4;
#pragma unroll
        for (int r = 0; r < 4; ++r)
          lds[(rl0 + r) * 128 + cl] = f2bf((acc[i][j][r] + bj) * 0.125f);
      }
    }
    __syncthreads();
#pragma unroll
    for (int it = 0; it < 8; ++it) {
      int c = tid + it * 256;
      int r = c >> 4, ck = c & 15;
      int grow = by * 128 + r;
      size_t base = ((size_t)grow * 8 + bx * 2 + (ck >> 3)) * 64 + (ck & 7) * 8;
      *(uint4*)(Qs + base) = *(const uint4*)&lds[r * 128 + ck * 8];
    }
  } else {
#pragma unroll
    for (int j = 0; j < 4; ++j) {
      int col = bx * 128 + wc * 64 + j * 16 + l15;
      float bj = bias[col];
      bool isK = col < 512;
      int cp = isK ? col : col - 512;
      int hh = cp >> 6, d = cp & 63;
#pragma unroll
      for (int i = 0; i < 4; ++i) {
        int row0 = by * 128 + wr * 64 + i * 16 + g * 4;
#pragma unroll
        for (int r = 0; r < 4; ++r) {
          int row = row0 + r;
          int b = row >> 8, kk = row & 255;
          ushort h = f2bf(acc[i][j][r] + bj);
          if (isK)
            Kq[((size_t)((b * 8 + hh) * 256) + kk) * 64 + d] = h;
          else
            Vt[((size_t)((b * 8 + hh) * 64) + d) * 256 + kk] = h;
        }
      }
    }
  }
}

// ---------------- conv body: one tap per block, bf16 partials out ----------------
__device__ __forceinline__ void conv_body(
    const ushort* __restrict__ xq, const ushort* __restrict__ Wsr_,
    ushort* __restrict__ part, int bx, int by, int z, ushort* lds) {
  int kh = z >> 2, kw = z & 3;
  int tid = threadIdx.x;
  int lane = tid & 63, w = tid >> 6;
  int wr = w >> 1, wc = w & 1;
  int l15 = lane & 15, g = lane >> 4;
  int srow = lane >> 3;
  int scol = (lane & 7) ^ srow;

  const ushort* aBase[4];
#pragma unroll
  for (int t = 0; t < 4; ++t) {
    int gm = by * 128 + w * 32 + t * 8 + srow;
    int xr = (gm >> 8) * 4096 + ((((gm >> 4) & 15) << 2) + kh) * 64 +
             ((gm & 15) << 2) + kw;
    aBase[t] = xq + (size_t)xr * 512 + scol * 8;
  }
  const ushort* bBase =
      Wsr_ + ((size_t)(z * 512 + bx * 128 + w * 32 + srow)) * 512 + scol * 8;

  f32x4 acc[4][4];
#pragma unroll
  for (int i = 0; i < 4; ++i)
#pragma unroll
    for (int j = 0; j < 4; ++j) acc[i][j] = (f32x4){0.f, 0.f, 0.f, 0.f};

#define STAGE_C(ks, buf)                                              \
  {                                                                   \
    int kk = (ks) * 64;                                               \
    ushort* aD = lds + (buf) * 16384 + w * 2048;                      \
    ushort* bD = lds + (buf) * 16384 + 8192 + w * 2048;               \
    _Pragma("unroll") for (int t = 0; t < 4; ++t) {                   \
      gload16(aBase[t] + kk, aD + t * 512);                           \
      gload16(bBase + (size_t)t * 4096 + kk, bD + t * 512);           \
    }                                                                 \
  }

#define COMPUTE_C(buf)                                                         \
  {                                                                            \
    const ushort* As = lds + (buf) * 16384;                                    \
    const ushort* Bs = As + 8192;                                              \
    _Pragma("unroll") for (int kk2 = 0; kk2 < 2; ++kk2) {                      \
      int rb = kk2 * 4 + g;                                                    \
      bf16x8 af[4], bg[4];                                                     \
      _Pragma("unroll") for (int i = 0; i < 4; ++i) {                          \
        int row = wr * 64 + i * 16 + l15;                                      \
        af[i] = *(const bf16x8*)&As[row * 64 + ((rb ^ (row & 7)) << 3)];       \
      }                                                                        \
      _Pragma("unroll") for (int j = 0; j < 4; ++j) {                          \
        int col = wc * 64 + j * 16 + l15;                                      \
        bg[j] = *(const bf16x8*)&Bs[col * 64 + ((rb ^ (col & 7)) << 3)];       \
      }                                                                        \
      _Pragma("unroll") for (int i = 0; i < 4; ++i)                            \
        _Pragma("unroll") for (int j = 0; j < 4; ++j)                          \
          acc[i][j] =                                                          \
              __builtin_amdgcn_mfma_f32_16x16x32_bf16(af[i], bg[j], acc[i][j], \
                                                      0, 0, 0);                \
    }                                                                          \
  }

  STAGE_C(0, 0);
  __syncthreads();
  for (int ks = 0; ks < 7; ++ks) {
    STAGE_C(ks + 1, (ks + 1) & 1);
    COMPUTE_C(ks & 1);
    __syncthreads();
  }
  COMPUTE_C(1);

#undef STAGE_C
#undef COMPUTE_C

  ushort* Cp = part + (size_t)z * 524288;
#pragma unroll
  for (int j = 0; j < 4; ++j) {
    int col = bx * 128 + wc * 64 + j * 16 + l15;
#pragma unroll
    for (int i = 0; i < 4; ++i) {
      int row0 = by * 128 + wr * 64 + i * 16 + g * 4;
#pragma unroll
      for (int r = 0; r < 4; ++r)
        Cp[(size_t)(row0 + r) * 512 + col] = f2bf(acc[i][j][r]);
    }
  }
}

// conv (512) + q-proj (512): 1024 uniform 8-step blocks — both depend only on prep.
__global__ __launch_bounds__(256) void cq_kernel(
    const ushort* __restrict__ xq, const ushort* __restrict__ Wsr_,
    ushort* __restrict__ part, const ushort* __restrict__ Wq_,
    const float* __restrict__ bq, ushort* __restrict__ Qs) {
  __shared__ __align__(16) ushort lds[32768];
  int bid = xcd_swz(blockIdx.x, 1024);
  if (bid < 512) {
    conv_body(xq, Wsr_, part, bid & 3, (bid >> 2) & 7, bid >> 5, lds);
  } else {
    int b2 = bid - 512;
    gemm_body<1>(xq, Wq_, bq, nullptr, Qs, nullptr, nullptr, 512,
                 b2 & 3, b2 >> 2, lds);
  }
}

// kv-proj alone: 64 uniform 8-step blocks (after ln)
__global__ __launch_bounds__(256) void kvproj_kernel(
    const ushort* __restrict__ xkv_, const ushort* __restrict__ Wkv_,
    const float* __restrict__ bkv, ushort* __restrict__ Kq,
    ushort* __restrict__ Vt) {
  __shared__ __align__(16) ushort lds[32768];
  int bid = xcd_swz(blockIdx.x, 64);
  gemm_body<2>(xkv_, Wkv_, bkv, nullptr, nullptr, Kq, Vt, 1024,
               bid & 7, bid >> 3, lds);
}

// out-proj
__global__ __launch_bounds__(256) void gemm_out_kernel(
    const ushort* __restrict__ A, const ushort* __restrict__ Bw,
    const float* __restrict__ bias, float* __restrict__ C) {
  __shared__ __align__(16) ushort lds[32768];
  int bid = xcd_swz(blockIdx.x, 512);
  gemm_body<0>(A, Bw, bias, C, nullptr, nullptr, nullptr, 512,
               bid & 3, bid >> 2, lds);
}

// ---------------- partial-sum(16, bf16) + bias + LayerNorm -> bf16 ----------------
__global__ __launch_bounds__(256) void ln_kernel(
    const ushort* __restrict__ part, const float* __restrict__ bsr,
    const float* __restrict__ gamma, const float* __restrict__ beta,
    ushort* __restrict__ xkv_) {
  int row = blockIdx.x;
  int t = threadIdx.x;
  float v0 = bsr[t], v1 = bsr[t + 256];
  for (int p = 0; p < 16; ++p) {
    v0 += bf2f(part[(size_t)p * 524288 + (size_t)row * 512 + t]);
    v1 += bf2f(part[(size_t)p * 524288 + (size_t)row * 512 + t + 256]);
  }
  float s = v0 + v1, sq = v0 * v0 + v1 * v1;
#pragma unroll
  for (int o = 1; o < 64; o <<= 1) {
    s += __shfl_xor(s, o);
    sq += __shfl_xor(sq, o);
  }
  __shared__ float red[8];
  int wv = t >> 6;
  if ((t & 63) == 0) { red[wv] = s; red[4 + wv] = sq; }
  __syncthreads();
  s = red[0] + red[1] + red[2] + red[3];
  sq = red[4] + red[5] + red[6] + red[7];
  float mu = s * (1.0f / 512.0f);
  float var = sq * (1.0f / 512.0f) - mu * mu;
  float rs = rsqrtf(var + 1e-5f);
  xkv_[(size_t)row * 512 + t] = f2bf((v0 - mu) * rs * gamma[t] + beta[t]);
  xkv_[(size_t)row * 512 + t + 256] =
      f2bf((v1 - mu) * rs * gamma[t + 256] + beta[t + 256]);
}

// ---------------- MFMA flash attention: 128 q/block, 1-term QK & PV ----------------
__global__ __launch_bounds__(256, 3) void attn_kernel(
    const ushort* __restrict__ Qs, const ushort* __restrict__ Kq,
    const ushort* __restrict__ Vt, ushort* __restrict__ attno) {
  __shared__ __align__(16) char arena[49152];
  ushort* KsL = (ushort*)arena;            // [2][64 kk][64], swizzled
  ushort* VtL = (ushort*)(arena + 16384);  // [2][64 d][64 kk], swizzled
  ushort* PL = (ushort*)(arena + 32768);   // [128 q][64 kk] bf16, swizzled
  float* ob = (float*)arena;               // epilogue alias

  int tid = threadIdx.x;
  int qb = blockIdx.x, h = blockIdx.y, b = blockIdx.z;
  int n0 = qb * 128, bh = b * 8 + h;
  int lane = tid & 63, w = tid >> 6;
  int q15 = lane & 15, g = lane >> 4;

  const ushort* kbase = Kq + (size_t)bh * 256 * 64;
  const ushort* vbase = Vt + (size_t)bh * 64 * 256;

  bf16x8 qf[2][2];
#pragma unroll
  for (int set = 0; set < 2; ++set) {
    const ushort* qptr =
        Qs + ((size_t)(b * 4096 + n0 + set * 64 + w * 16 + q15) * 8 + h) * 64;
#pragma unroll
    for (int kb = 0; kb < 2; ++kb)
      qf[set][kb] = *(const bf16x8*)(qptr + kb * 32 + g * 8);
  }

  f32x4 accO[2][4];
#pragma unroll
  for (int set = 0; set < 2; ++set)
#pragma unroll
    for (int t = 0; t < 4; ++t) accO[set][t] = (f32x4){0.f, 0.f, 0.f, 0.f};
  float m[2] = {-1e30f, -1e30f}, l[2] = {0.f, 0.f};

#define STAGE_A(cc, buf)                                                     \
  {                                                                          \
    _Pragma("unroll") for (int i = 0; i < 2; ++i) {                          \
      int rb_ = w * 16 + i * 8;                                              \
      int r_ = rb_ + (lane >> 3);                                            \
      int sb_ = (lane & 7) ^ (r_ & 7);                                       \
      gload16(kbase + (size_t)((cc) * 64 + r_) * 64 + (sb_ << 3),            \
              KsL + (buf) * 4096 + rb_ * 64);                                \
      gload16(vbase + (size_t)r_ * 256 + (cc) * 64 + (sb_ << 3),             \
              VtL + (buf) * 4096 + rb_ * 64);                                \
    }                                                                        \
  }

  STAGE_A(0, 0);
  __syncthreads();

  for (int c = 0; c < 4; ++c) {
    int buf = c & 1;
    if (c < 3) STAGE_A(c + 1, buf ^ 1);
    const ushort* Ks = KsL + buf * 4096;
    const ushort* Vs = VtL + buf * 4096;

    f32x4 accS[2][4];
#pragma unroll
    for (int set = 0; set < 2; ++set)
#pragma unroll
      for (int t = 0; t < 4; ++t) accS[set][t] = (f32x4){0.f, 0.f, 0.f, 0.f};
#pragma unroll
    for (int kb = 0; kb < 2; ++kb) {
      bf16x8 ak[4];
#pragma unroll
      for (int t = 0; t < 4; ++t) {
        int kkr = t * 16 + q15;
        ak[t] = *(const bf16x8*)&Ks[kkr * 64 + (((kb * 4 + g) ^ (kkr & 7)) << 3)];
      }
#pragma unroll
      for (int set = 0; set < 2; ++set)
#pragma unroll
        for (int t = 0; t < 4; ++t)
          accS[set][t] = __builtin_amdgcn_mfma_f32_16x16x32_bf16(
              ak[t], qf[set][kb], accS[set][t], 0, 0, 0);
    }

#pragma unroll
    for (int set = 0; set < 2; ++set) {
      int qrowL = set * 64 + w * 16 + q15;
      float mx = -1e30f;
#pragma unroll
      for (int t = 0; t < 4; ++t)
#pragma unroll
        for (int r = 0; r < 4; ++r) mx = fmaxf(mx, accS[set][t][r]);
      mx = fmaxf(mx, __shfl_xor(mx, 16));
      mx = fmaxf(mx, __shfl_xor(mx, 32));
      float mn = fmaxf(m[set], mx);
      float fac = __expf(m[set] - mn);
      m[set] = mn;
      float sum = 0.f;
      ushort ph[4][4];
#pragma unroll
      for (int t = 0; t < 4; ++t)
#pragma unroll
        for (int r = 0; r < 4; ++r) {
          float p = __expf(accS[set][t][r] - mn);
          ushort hp = f2bf(p);
          ph[t][r] = hp;
          sum += bf2f(hp);
        }
      sum += __shfl_xor(sum, 16);
      sum += __shfl_xor(sum, 32);
      l[set] = l[set] * fac + sum;
#pragma unroll
      for (int t = 0; t < 4; ++t) {
        accO[set][t][0] *= fac; accO[set][t][1] *= fac;
        accO[set][t][2] *= fac; accO[set][t][3] *= fac;
      }
#pragma unroll
      for (int t = 0; t < 4; ++t)
#pragma unroll
        for (int rp = 0; rp < 4; rp += 2) {
          uint u = ph[t][rp] | ((uint)ph[t][rp + 1] << 16);
          int kkl = t * 16 + g * 4 + rp;
          int blk = kkl >> 3, off = kkl & 7;
          *(uint*)((char*)PL + qrowL * 128 + ((blk ^ (q15 & 7)) << 4) + off * 2) = u;
        }
    }
    __syncthreads();

    bf16x8 pf[2][2];
#pragma unroll
    for (int set = 0; set < 2; ++set) {
      int qrowL = set * 64 + w * 16 + q15;
#pragma unroll
      for (int kb = 0; kb < 2; ++kb)
        pf[set][kb] = *(const bf16x8*)((char*)PL + qrowL * 128 +
                                       (((kb * 4 + g) ^ (q15 & 7)) << 4));
    }
#pragma unroll
    for (int kb = 0; kb < 2; ++kb)
#pragma unroll
      for (int t = 0; t < 4; ++t) {
        int d = t * 16 + q15;
        bf16x8 vf =
            *(const bf16x8*)&Vs[d * 64 + (((kb * 4 + g) ^ (d & 7)) << 3)];
        accO[0][t] = __builtin_amdgcn_mfma_f32_16x16x32_bf16(vf, pf[0][kb],
                                                             accO[0][t], 0, 0, 0);
        accO[1][t] = __builtin_amdgcn_mfma_f32_16x16x32_bf16(vf, pf[1][kb],
                                                             accO[1][t], 0, 0, 0);
      }
    __syncthreads();
  }
#undef STAGE_A

#pragma unroll
  for (int set = 0; set < 2; ++set) {
    if (set) __syncthreads();
    float inv = 1.0f / l[set];
#pragma unroll
    for (int t = 0; t < 4; ++t)
#pragma unroll
      for (int r = 0; r < 4; ++r)
        ob[(t * 16 + g * 4 + r) * 68 + w * 16 + q15] = accO[set][t][r] * inv;
    __syncthreads();
#pragma unroll
    for (int i = 0; i < 2; ++i) {
      int idx = tid + i * 256;
      int qq = idx >> 3, d8 = (idx & 7) << 3;
      ushort hh[8];
#pragma unroll
      for (int jj = 0; jj < 8; ++jj) hh[jj] = f2bf(ob[(d8 + jj) * 68 + qq]);
      uint4 hp;
      hp.x = hh[0] | ((uint)hh[1] << 16); hp.y = hh[2] | ((uint)hh[3] << 16);
      hp.z = hh[4] | ((uint)hh[5] << 16); hp.w = hh[6] | ((uint)hh[7] << 16);
      size_t rowb = (size_t)(b * 4096 + n0 + set * 64 + qq) * 512 + h * 64 + d8;
      *(uint4*)(attno + rowb) = hp;
    }
  }
}

// ---------------- launch ----------------
extern "C" void kernel_launch(void* const* d_in, const int* in_sizes, int n_in,
                              void* d_out, int out_size, void* d_ws, size_t ws_size,
                              hipStream_t stream) {
  const float* x     = (const float*)d_in[0];
  const float* Wq    = (const float*)d_in[1];
  const float* bq    = (const float*)d_in[2];
  const float* Wk    = (const float*)d_in[3];
  const float* bk    = (const float*)d_in[4];
  const float* Wv    = (const float*)d_in[5];
  const float* bv    = (const float*)d_in[6];
  const float* Wp    = (const float*)d_in[7];
  const float* bp    = (const float*)d_in[8];
  const float* Wsr   = (const float*)d_in[9];
  const float* bsr   = (const float*)d_in[10];
  const float* gamma = (const float*)d_in[11];
  const float* beta  = (const float*)d_in[12];

  float* ws = (float*)d_ws;
  // Layout (~47MB). NOTE: Qsplit gets its own region now — conv_part and
  // Qsplit are written CONCURRENTLY in cq_kernel (no aliasing).
  ushort* xq     = (ushort*)ws;                        // 8,388,608 us
  ushort* attno_ = (ushort*)ws;                        // aliases xq after qkv
  ushort* conv_part = (ushort*)(ws + 4194304);         // 8,388,608 us
  ushort* Qsplit = (ushort*)(ws + 8388608);            // 8,388,608 us
  ushort* Wsr_ = (ushort*)(ws + 12582912);             // 4,194,304 us
  float*  rest = ws + 14680064;
  ushort* Wq_  = (ushort*)rest;                 // 262,144 us = 131,072 fl
  ushort* Wp_  = (ushort*)(rest + 131072);      // 262,144 us
  ushort* Wkv_ = (ushort*)(rest + 262144);      // 524,288 us = 262,144 fl
  ushort* xkv_ = (ushort*)(rest + 524288);      // 524,288 us
  ushort* Kq   = (ushort*)(rest + 786432);      // 524,288 us
  ushort* Vt   = (ushort*)(rest + 1048576);     // 524,288 us
  float*  bkv  = rest + 1310720;                // 1,024 fl
  float* outp = (float*)d_out;

  prep_kernel<<<8705, 256, 0, stream>>>(x, Wq, Wp, Wk, Wv, Wsr, bk, bv,
                                        xq, Wq_, Wp_, Wkv_, Wsr_, bkv);
  // conv + q-proj together: both depend only on prep outputs.
  cq_kernel<<<1024, 256, 0, stream>>>(xq, Wsr_, conv_part, Wq_, bq, Qsplit);
  ln_kernel<<<1024, 256, 0, stream>>>(conv_part, bsr, gamma, beta, xkv_);
  kvproj_kernel<<<64, 256, 0, stream>>>(xkv_, Wkv_, bkv, Kq, Vt);
  attn_kernel<<<dim3(32, 8, 4), 256, 0, stream>>>(Qsplit, Kq, Vt, attno_);
  gemm_out_kernel<<<512, 256, 0, stream>>>(attno_, Wp_, bp, outp);
}